// Round 1
// baseline (1380.536 us; speedup 1.0000x reference)
//
#include <hip/hip_runtime.h>
#include <hip/hip_bf16.h>
#include <math.h>

// ---- problem constants ----
#define BATCH   2
#define TSEQ    512
#define NDIM    256
#define STRIDE_ 4
#define KLEN    14
#define DM      3584        // NDIM*KLEN
#define DI      7168        // 2*DM
#define DTR     224
#define DSTATE  16
#define NCLS    41
#define LOUT    125
#define LPAD    128         // padded rows per batch
#define MROWS   256         // BATCH*LPAD

typedef __attribute__((ext_vector_type(8))) short bf8_t;   // 8 bf16
typedef __attribute__((ext_vector_type(4))) float f4_t;    // 4 fp32 acc

// fp32 -> bf16 RNE, two at a time
__device__ inline unsigned bfpair(float a, float b) {
    unsigned ua = __builtin_bit_cast(unsigned, a);
    unsigned ub = __builtin_bit_cast(unsigned, b);
    ua = (ua + 0x7fffu + ((ua >> 16) & 1u)) >> 16;
    ub = (ub + 0x7fffu + ((ub >> 16) & 1u)) >> 16;
    return ua | (ub << 16);
}
__device__ inline uint4 pack8(float4 a, float4 b) {
    return make_uint4(bfpair(a.x, a.y), bfpair(a.z, a.w),
                      bfpair(b.x, b.y), bfpair(b.z, b.w));
}

// ---------------------------------------------------------------------------
// day projection + softsign
__global__ void day_proj(const float* __restrict__ nI, const float* __restrict__ dw,
                         const float* __restrict__ db, const int* __restrict__ dayIdx,
                         float* __restrict__ t_full) {
    int bi = blockIdx.x;               // b*512 + i
    int b = bi >> 9;
    int di = dayIdx[b];
    int tid = threadIdx.x;             // k
    __shared__ float a_sh[256];
    a_sh[tid] = nI[(size_t)bi * 256 + tid];
    __syncthreads();
    const float* w = dw + (size_t)di * 65536;
    float acc = db[(size_t)di * 256 + tid];
    #pragma unroll 8
    for (int d = 0; d < 256; ++d) acc = fmaf(a_sh[d], w[d * 256 + tid], acc);
    t_full[(size_t)bi * 256 + tid] = acc / (1.f + fabsf(acc));
}

// window gather + zero the pad rows (l >= 125)
__global__ void window_k(const float* __restrict__ t_full, float* __restrict__ res) {
    int bl = blockIdx.x;               // 0..255
    int b = bl >> 7, l = bl & 127;
    size_t m = (size_t)b * LPAD + l;
    if (l >= LOUT) {
        for (int c = threadIdx.x; c < DM; c += 256) res[m * DM + c] = 0.f;
        return;
    }
    for (int c = threadIdx.x; c < DM; c += 256) {
        int d = c / KLEN, j = c - d * KLEN;
        res[m * DM + c] = t_full[((size_t)b * TSEQ + l * STRIDE_ + j) * 256 + d];
    }
}

// layernorm over DM -> packed bf16 A in fragment-major [G=k/8][m][8]
__global__ void ln_pack(const float* __restrict__ res, const float* __restrict__ w,
                        const float* __restrict__ b, short* __restrict__ hnp) {
    int m = blockIdx.x, tid = threadIdx.x;
    const float* row = res + (size_t)m * DM;
    float s = 0.f, ss = 0.f;
    for (int c = tid; c < DM; c += 256) { float v = row[c]; s += v; ss += v * v; }
    #pragma unroll
    for (int o = 32; o; o >>= 1) { s += __shfl_xor(s, o); ss += __shfl_xor(ss, o); }
    __shared__ float sm[8];
    int wid = tid >> 6;
    if ((tid & 63) == 0) { sm[wid] = s; sm[4 + wid] = ss; }
    __syncthreads();
    s = sm[0] + sm[1] + sm[2] + sm[3];
    ss = sm[4] + sm[5] + sm[6] + sm[7];
    float mu = s * (1.f / DM);
    float var = ss * (1.f / DM) - mu * mu;
    float rs = rsqrtf(var + 1e-5f);
    for (int G = tid; G < DM / 8; G += 256) {
        float4 f0 = *(const float4*)(row + G * 8);
        float4 f1 = *(const float4*)(row + G * 8 + 4);
        float4 w0 = *(const float4*)(w + G * 8);
        float4 w1 = *(const float4*)(w + G * 8 + 4);
        float4 b0 = *(const float4*)(b + G * 8);
        float4 b1 = *(const float4*)(b + G * 8 + 4);
        f0.x = (f0.x - mu) * rs * w0.x + b0.x; f0.y = (f0.y - mu) * rs * w0.y + b0.y;
        f0.z = (f0.z - mu) * rs * w0.z + b0.z; f0.w = (f0.w - mu) * rs * w0.w + b0.w;
        f1.x = (f1.x - mu) * rs * w1.x + b1.x; f1.y = (f1.y - mu) * rs * w1.y + b1.y;
        f1.z = (f1.z - mu) * rs * w1.z + b1.z; f1.w = (f1.w - mu) * rs * w1.w + b1.w;
        *(uint4*)&hnp[((size_t)G * 256 + m) * 8] = pack8(f0, f1);
    }
}

// generic fp32 row-major -> packed bf16 [G][m][8]; one block per row m
__global__ void pack_rows(const float* __restrict__ src, int lda, int nG,
                          short* __restrict__ dst) {
    int m = blockIdx.x;
    const float* row = src + (size_t)m * lda;
    for (int G = threadIdx.x; G < nG; G += 256) {
        float4 f0 = *(const float4*)(row + G * 8);
        float4 f1 = *(const float4*)(row + G * 8 + 4);
        *(uint4*)&dst[((size_t)G * 256 + m) * 8] = pack8(f0, f1);
    }
}

__global__ void zero_k(float* __restrict__ p) {
    size_t i = (size_t)(blockIdx.x * 256 + threadIdx.x) * 4;
    *(float4*)(p + i) = make_float4(0.f, 0.f, 0.f, 0.f);
}

// ---------------------------------------------------------------------------
// MFMA GEMM, double-buffered: C[256 x N] (+)= A[256 x K] * W[N x K]^T
// A pre-packed bf16 fragment-major [G=k/8][m][8], staged via global_load_lds DMA.
// W fp32, cooperatively loaded (coalesced 128B row segments), packed to bf16 LDS.
// Block tile 256 x NT (NT=32 or 64), BK=32, 4 waves.
// NT=32 doubles grid occupancy at constant total W traffic (latency-bound fix).
// EPI: 0=store, 1=softplus(bias+acc), 2=atomicAdd
template <int EPI, int NT>
__global__ __launch_bounds__(256)
void gemm_mfma(const short* __restrict__ Ap, const float* __restrict__ W, int ldw,
               float* __restrict__ C, int ldc, int kSteps,
               const float* __restrict__ bias) {
    constexpr int NC = NT / 16;                       // col fragments per wave
    __shared__ __align__(16) short a_sh[2][4][2056];  // [buf][kgroup][m*8]
    __shared__ __align__(16) short w_sh[2][4][NT * 8 + 8];
    const int tid = threadIdx.x;
    const int wz = tid >> 6, lane = tid & 63;
    const int g = lane >> 4, i16 = lane & 15;
    const int n0 = blockIdx.x * NT;
    const int sBeg = blockIdx.z * kSteps, sEnd = sBeg + kSteps;
    const int wr = tid >> 3;      // 0..31 (row within tile, +32 for second half)
    const int wq = tid & 7;       // quad-of-4-floats within 32-k

    f4_t acc[4][NC];
    #pragma unroll
    for (int r = 0; r < 4; ++r)
        #pragma unroll
        for (int c = 0; c < NC; ++c) acc[r][c] = (f4_t){0.f, 0.f, 0.f, 0.f};

    const short* arow = Ap + (size_t)tid * 8;
    const float* wbase  = W + (size_t)(n0 + wr) * ldw + wq * 4;
    const float* wbase2 = wbase + (size_t)32 * ldw;   // only valid when NT==64

    // ---- prologue: fill buffer 0 for step sBeg ----
    float4 wv0 = *(const float4*)(wbase + (size_t)sBeg * 32);
    float4 wv1;
    if constexpr (NT == 64) wv1 = *(const float4*)(wbase2 + (size_t)sBeg * 32);
    #pragma unroll
    for (int it = 0; it < 4; ++it)
        __builtin_amdgcn_global_load_lds(
            (const __attribute__((address_space(1))) unsigned int*)(arow + (size_t)(sBeg * 4 + it) * 2048),
            (__attribute__((address_space(3))) unsigned int*)&a_sh[0][it][tid * 8], 16, 0, 0);
    {
        uint2 p0 = {bfpair(wv0.x, wv0.y), bfpair(wv0.z, wv0.w)};
        *(uint2*)&w_sh[0][wq >> 1][wr * 8 + (wq & 1) * 4] = p0;
        if constexpr (NT == 64) {
            uint2 p1 = {bfpair(wv1.x, wv1.y), bfpair(wv1.z, wv1.w)};
            *(uint2*)&w_sh[0][wq >> 1][(wr + 32) * 8 + (wq & 1) * 4] = p1;
        }
    }
    int s1 = (sBeg + 1 < sEnd) ? sBeg + 1 : sEnd - 1;
    wv0 = *(const float4*)(wbase + (size_t)s1 * 32);
    if constexpr (NT == 64) wv1 = *(const float4*)(wbase2 + (size_t)s1 * 32);

    for (int s = sBeg; s < sEnd; ++s) {
        const int cur = (s - sBeg) & 1, nxt = cur ^ 1;
        __syncthreads();   // a_sh[cur]/w_sh[cur] ready; [nxt] free (readers done pre-prev barrier)
        if (s + 1 < sEnd) {
            #pragma unroll
            for (int it = 0; it < 4; ++it)
                __builtin_amdgcn_global_load_lds(
                    (const __attribute__((address_space(1))) unsigned int*)(arow + (size_t)((s + 1) * 4 + it) * 2048),
                    (__attribute__((address_space(3))) unsigned int*)&a_sh[nxt][it][tid * 8], 16, 0, 0);
            uint2 p0 = {bfpair(wv0.x, wv0.y), bfpair(wv0.z, wv0.w)};
            *(uint2*)&w_sh[nxt][wq >> 1][wr * 8 + (wq & 1) * 4] = p0;
            if constexpr (NT == 64) {
                uint2 p1 = {bfpair(wv1.x, wv1.y), bfpair(wv1.z, wv1.w)};
                *(uint2*)&w_sh[nxt][wq >> 1][(wr + 32) * 8 + (wq & 1) * 4] = p1;
            }
            int s2 = (s + 2 < sEnd) ? s + 2 : sEnd - 1;
            wv0 = *(const float4*)(wbase + (size_t)s2 * 32);
            if constexpr (NT == 64) wv1 = *(const float4*)(wbase2 + (size_t)s2 * 32);
        }
        bf8_t af[4], wf[NC];
        #pragma unroll
        for (int r = 0; r < 4; ++r)
            af[r] = *(const bf8_t*)&a_sh[cur][g][(wz * 64 + r * 16 + i16) * 8];
        #pragma unroll
        for (int c = 0; c < NC; ++c)
            wf[c] = *(const bf8_t*)&w_sh[cur][g][(c * 16 + i16) * 8];
        #pragma unroll
        for (int r = 0; r < 4; ++r)
            #pragma unroll
            for (int c = 0; c < NC; ++c)
                acc[r][c] = __builtin_amdgcn_mfma_f32_16x16x32_bf16(af[r], wf[c], acc[r][c], 0, 0, 0);
    }

    float bv[NC];
    if (EPI == 1) {
        #pragma unroll
        for (int c = 0; c < NC; ++c) bv[c] = bias[n0 + c * 16 + i16];
    }
    #pragma unroll
    for (int r = 0; r < 4; ++r) {
        #pragma unroll
        for (int c = 0; c < NC; ++c) {
            int n = n0 + c * 16 + i16;
            #pragma unroll
            for (int v = 0; v < 4; ++v) {
                int m = wz * 64 + r * 16 + g * 4 + v;
                float val = acc[r][c][v];
                if (EPI == 0) {
                    C[(size_t)m * ldc + n] = val;
                } else if (EPI == 1) {
                    val += bv[c];
                    C[(size_t)m * ldc + n] = (val > 20.f) ? val : log1pf(expf(val));
                } else {
                    atomicAdd(&C[(size_t)m * ldc + n], val);
                }
            }
        }
    }
}

// causal depthwise conv (DCONV=4) + silu; writes fp32 xq AND packed bf16 xqp
__global__ void conv_silu_pack(const float* __restrict__ xz, const float* __restrict__ cw,
                               const float* __restrict__ cb, float* __restrict__ xq,
                               short* __restrict__ xqp) {
    int bl = blockIdx.x;
    int b = bl / 125, l = bl % 125;
    size_t m = (size_t)b * LPAD + l;
    for (int c0 = threadIdx.x * 8; c0 < DI; c0 += 2048) {
        float v[8];
        float4 cb0 = *(const float4*)(cb + c0);
        float4 cb1 = *(const float4*)(cb + c0 + 4);
        v[0] = cb0.x; v[1] = cb0.y; v[2] = cb0.z; v[3] = cb0.w;
        v[4] = cb1.x; v[5] = cb1.y; v[6] = cb1.z; v[7] = cb1.w;
        #pragma unroll
        for (int j = 0; j < 4; ++j) {
            int lj = l - 3 + j;
            if (lj < 0) continue;
            const float* xr = xz + ((size_t)b * LPAD + lj) * (2 * DI) + c0;
            float4 x0 = *(const float4*)xr;
            float4 x1 = *(const float4*)(xr + 4);
            float xa[8] = {x0.x, x0.y, x0.z, x0.w, x1.x, x1.y, x1.z, x1.w};
            #pragma unroll
            for (int k = 0; k < 8; ++k)
                v[k] = fmaf(xa[k], cw[(c0 + k) * 4 + j], v[k]);
        }
        float4 o0, o1;
        #pragma unroll
        for (int k = 0; k < 8; ++k) {
            float sv = v[k] / (1.f + expf(-v[k]));
            if (k < 4) (&o0.x)[k] = sv; else (&o1.x)[k - 4] = sv;
        }
        *(float4*)(xq + m * DI + c0) = o0;
        *(float4*)(xq + m * DI + c0 + 4) = o1;
        *(uint4*)&xqp[(((size_t)c0 / 8) * 256 + m) * 8] = pack8(o0, o1);
    }
}

// selective scan: 4 threads per channel (4 states each), software-pipelined.
// Quad lanes (tid&3 = state group) share one channel; yv combined via shfl_xor.
// 4x block count vs 1-thread-per-channel (224 blocks): hides expf+load latency.
__global__ void scan_kernel(const float* __restrict__ delta, const float* __restrict__ xq,
                            const float* __restrict__ xdbl, const float* __restrict__ xz,
                            const float* __restrict__ Alog, const float* __restrict__ Dp,
                            float* __restrict__ y) {
    int tid = threadIdx.x;
    int sg = tid & 3;                          // state group: states sg*4..sg*4+3
    int c = blockIdx.x * 64 + (tid >> 2);      // channel 0..7167
    int b = blockIdx.y;
    float As[4], st[4];
    #pragma unroll
    for (int k = 0; k < 4; ++k) {
        As[k] = -expf(Alog[(size_t)c * DSTATE + sg * 4 + k]);
        st[k] = 0.f;
    }
    float dp = Dp[c];
    size_t mb = (size_t)b * LPAD;
    // prefetch l=0
    float d_c = delta[mb * DI + c];
    float x_c = xq[mb * DI + c];
    float z_c = xz[mb * (2 * DI) + DI + c];
    float4 B_c = *(const float4*)(xdbl + mb * 256 + DTR + sg * 4);
    float4 C_c = *(const float4*)(xdbl + mb * 256 + DTR + DSTATE + sg * 4);
    for (int l = 0; l < LOUT; ++l) {
        float d_n = d_c, x_n = x_c, z_n = z_c;
        float4 B_n = B_c, C_n = C_c;
        if (l + 1 < LOUT) {
            size_t m = mb + l + 1;
            d_n = delta[m * DI + c];
            x_n = xq[m * DI + c];
            z_n = xz[m * (2 * DI) + DI + c];
            B_n = *(const float4*)(xdbl + m * 256 + DTR + sg * 4);
            C_n = *(const float4*)(xdbl + m * 256 + DTR + DSTATE + sg * 4);
        }
        float du = d_c * x_c;
        float yv = 0.f;
        #pragma unroll
        for (int k = 0; k < 4; ++k) {
            st[k] = fmaf(expf(d_c * As[k]), st[k], du * (&B_c.x)[k]);
            yv = fmaf(st[k], (&C_c.x)[k], yv);
        }
        yv += __shfl_xor(yv, 1);
        yv += __shfl_xor(yv, 2);
        if (sg == 0)
            y[(mb + l) * DI + c] = (yv + x_c * dp) * (z_c / (1.f + expf(-z_c)));
        d_c = d_n; x_c = x_n; z_c = z_n; B_c = B_n; C_c = C_n;
    }
}

// final layernorm + fc head
__global__ void ln_fc(const float* __restrict__ res, const float* __restrict__ wf,
                      const float* __restrict__ bf, const float* __restrict__ fcw,
                      const float* __restrict__ fcb, float* __restrict__ out) {
    __shared__ __align__(16) float hs[DM];
    __shared__ float sm[8];
    int bl = blockIdx.x;
    int b = bl / 125, l = bl % 125;
    size_t m = (size_t)b * LPAD + l;
    int tid = threadIdx.x;
    const float* row = res + m * DM;
    float s = 0.f, ss = 0.f;
    for (int c = tid; c < DM; c += 256) { float v = row[c]; s += v; ss += v * v; }
    #pragma unroll
    for (int o = 32; o; o >>= 1) { s += __shfl_xor(s, o); ss += __shfl_xor(ss, o); }
    int wid = tid >> 6;
    if ((tid & 63) == 0) { sm[wid] = s; sm[4 + wid] = ss; }
    __syncthreads();
    s = sm[0] + sm[1] + sm[2] + sm[3];
    ss = sm[4] + sm[5] + sm[6] + sm[7];
    float mu = s * (1.f / DM);
    float var = ss * (1.f / DM) - mu * mu;
    float rs = rsqrtf(var + 1e-5f);
    for (int c = tid; c < DM; c += 256) hs[c] = (row[c] - mu) * rs * wf[c] + bf[c];
    __syncthreads();
    int lane = tid & 63;
    for (int n = wid; n < NCLS; n += 4) {
        const float* wrow = fcw + (size_t)n * DM;
        float a0 = 0.f, a1 = 0.f, a2 = 0.f, a3 = 0.f;
        for (int k = lane; k < DM; k += 256) {
            a0 = fmaf(hs[k],       wrow[k],       a0);
            a1 = fmaf(hs[k + 64],  wrow[k + 64],  a1);
            a2 = fmaf(hs[k + 128], wrow[k + 128], a2);
            a3 = fmaf(hs[k + 192], wrow[k + 192], a3);
        }
        float acc = (a0 + a1) + (a2 + a3);
        #pragma unroll
        for (int o = 32; o; o >>= 1) acc += __shfl_xor(acc, o);
        if (lane == 0) out[((size_t)b * LOUT + l) * NCLS + n] = acc + fcb[n];
    }
}

// ---------------------------------------------------------------------------
extern "C" void kernel_launch(void* const* d_in, const int* in_sizes, int n_in,
                              void* d_out, int out_size, void* d_ws, size_t ws_size,
                              hipStream_t stream) {
    (void)in_sizes; (void)n_in; (void)out_size; (void)ws_size;
    const float* nI   = (const float*)d_in[0];
    const float* dw   = (const float*)d_in[1];
    const float* db   = (const float*)d_in[2];
    const float* nw   = (const float*)d_in[3];
    const float* nb   = (const float*)d_in[4];
    const float* ipw  = (const float*)d_in[5];
    const float* cw   = (const float*)d_in[6];
    const float* cb   = (const float*)d_in[7];
    const float* xpw  = (const float*)d_in[8];
    const float* dtw  = (const float*)d_in[9];
    const float* dtb  = (const float*)d_in[10];
    const float* Alog = (const float*)d_in[11];
    const float* Dp   = (const float*)d_in[12];
    const float* opw  = (const float*)d_in[13];
    const float* nfw  = (const float*)d_in[14];
    const float* nfb  = (const float*)d_in[15];
    const float* fcw  = (const float*)d_in[16];
    const float* fcb  = (const float*)d_in[17];
    const int*   dayI = (const int*)d_in[18];
    float* out = (float*)d_out;

    float* wsf = (float*)d_ws;
    float* t_full = wsf; wsf += 262144;                 // B*T*ND
    float* res    = wsf; wsf += (size_t)MROWS * DM;
    float* xz     = wsf; wsf += (size_t)MROWS * 2 * DI;
    float* xq     = wsf; wsf += (size_t)MROWS * DI;
    float* xdbl   = wsf; wsf += (size_t)MROWS * 256;
    float* delta  = wsf; wsf += (size_t)MROWS * DI;
    float* yb     = wsf; wsf += (size_t)MROWS * DI;
    short* wss = (short*)wsf;
    short* hnp   = wss; wss += (size_t)MROWS * DM;      // packed bf16
    short* xqp   = wss; wss += (size_t)MROWS * DI;
    short* xdblp = wss; wss += (size_t)MROWS * DTR;
    short* ybp   = wss; wss += (size_t)MROWS * DI;

    day_proj<<<dim3(BATCH * TSEQ), 256, 0, stream>>>(nI, dw, db, dayI, t_full);
    window_k<<<dim3(MROWS), 256, 0, stream>>>(t_full, res);

    for (int i = 0; i < 2; ++i) {
        ln_pack<<<dim3(MROWS), 256, 0, stream>>>(res, nw + (size_t)i * DM, nb + (size_t)i * DM, hnp);
        // xz = hn @ ipw^T   (N=14336, K=3584): 448 blocks (NT=32), 112 k-steps
        gemm_mfma<0, 32><<<dim3(448, 1, 1), 256, 0, stream>>>(
            hnp, ipw + (size_t)i * 2 * DI * DM, DM, xz, 2 * DI, 112, nullptr);
        conv_silu_pack<<<dim3(BATCH * LOUT), 256, 0, stream>>>(
            xz, cw + (size_t)i * DI * 4, cb + (size_t)i * DI, xq, xqp);
        zero_k<<<dim3(64), 256, 0, stream>>>(xdbl);
        // xdbl += xq @ xpw^T (N=256, K=7168): NT=32, splitK=28 -> 224 blocks
        gemm_mfma<2, 32><<<dim3(8, 1, 28), 256, 0, stream>>>(
            xqp, xpw + (size_t)i * 256 * DI, DI, xdbl, 256, 8, nullptr);
        pack_rows<<<dim3(MROWS), 256, 0, stream>>>(xdbl, 256, DTR / 8, xdblp);
        // delta = softplus(xdbl[:, :224] @ dtw^T + dtb)  (N=7168, K=224): 224 blocks
        gemm_mfma<1, 32><<<dim3(224, 1, 1), 256, 0, stream>>>(
            xdblp, dtw + (size_t)i * DI * DTR, DTR, delta, DI, 7, dtb + (size_t)i * DI);
        scan_kernel<<<dim3(DI / 64, BATCH), 256, 0, stream>>>(
            delta, xq, xdbl, xz, Alog + (size_t)i * DI * DSTATE, Dp + (size_t)i * DI, yb);
        pack_rows<<<dim3(MROWS), 256, 0, stream>>>(yb, DI, DI / 8, ybp);
        // res += yb @ opw^T  (N=3584, K=7168): NT=32, splitK=4 -> 448 blocks, half the atomics
        gemm_mfma<2, 32><<<dim3(112, 1, 4), 256, 0, stream>>>(
            ybp, opw + (size_t)i * DM * DI, DI, res, DM, 56, nullptr);
    }

    ln_fc<<<dim3(BATCH * LOUT), 256, 0, stream>>>(res, nfw, nfb, fcw, fcb, out);
}

// Round 2
// 1287.278 us; speedup vs baseline: 1.0724x; 1.0724x over previous
//
#include <hip/hip_runtime.h>
#include <hip/hip_bf16.h>
#include <math.h>

// ---- problem constants ----
#define BATCH   2
#define TSEQ    512
#define NDIM    256
#define STRIDE_ 4
#define KLEN    14
#define DM      3584        // NDIM*KLEN
#define DI      7168        // 2*DM
#define DTR     224
#define DSTATE  16
#define NCLS    41
#define LOUT    125
#define LPAD    128         // padded rows per batch
#define MROWS   256         // BATCH*LPAD

typedef __attribute__((ext_vector_type(8))) short bf8_t;   // 8 bf16
typedef __attribute__((ext_vector_type(4))) float f4_t;    // 4 fp32 acc

// fp32 -> bf16 RNE, two at a time
__device__ inline unsigned bfpair(float a, float b) {
    unsigned ua = __builtin_bit_cast(unsigned, a);
    unsigned ub = __builtin_bit_cast(unsigned, b);
    ua = (ua + 0x7fffu + ((ua >> 16) & 1u)) >> 16;
    ub = (ub + 0x7fffu + ((ub >> 16) & 1u)) >> 16;
    return ua | (ub << 16);
}
__device__ inline uint4 pack8(float4 a, float4 b) {
    return make_uint4(bfpair(a.x, a.y), bfpair(a.z, a.w),
                      bfpair(b.x, b.y), bfpair(b.z, b.w));
}

// ---------------------------------------------------------------------------
// day projection + softsign
__global__ void day_proj(const float* __restrict__ nI, const float* __restrict__ dw,
                         const float* __restrict__ db, const int* __restrict__ dayIdx,
                         float* __restrict__ t_full) {
    int bi = blockIdx.x;               // b*512 + i
    int b = bi >> 9;
    int di = dayIdx[b];
    int tid = threadIdx.x;             // k
    __shared__ float a_sh[256];
    a_sh[tid] = nI[(size_t)bi * 256 + tid];
    __syncthreads();
    const float* w = dw + (size_t)di * 65536;
    float acc = db[(size_t)di * 256 + tid];
    #pragma unroll 8
    for (int d = 0; d < 256; ++d) acc = fmaf(a_sh[d], w[d * 256 + tid], acc);
    t_full[(size_t)bi * 256 + tid] = acc / (1.f + fabsf(acc));
}

// window gather + zero the pad rows (l >= 125)
__global__ void window_k(const float* __restrict__ t_full, float* __restrict__ res) {
    int bl = blockIdx.x;               // 0..255
    int b = bl >> 7, l = bl & 127;
    size_t m = (size_t)b * LPAD + l;
    if (l >= LOUT) {
        for (int c = threadIdx.x; c < DM; c += 256) res[m * DM + c] = 0.f;
        return;
    }
    for (int c = threadIdx.x; c < DM; c += 256) {
        int d = c / KLEN, j = c - d * KLEN;
        res[m * DM + c] = t_full[((size_t)b * TSEQ + l * STRIDE_ + j) * 256 + d];
    }
}

// layernorm over DM -> packed bf16 A in fragment-major [G=k/8][m][8].
// ADD variant fuses: res += sum of 4 out_proj splitK partials (residual add),
// writes res back, LNs the updated row. Row staged in LDS to avoid re-read.
template <bool ADD>
__global__ void ln_pack(float* __restrict__ res, const float* __restrict__ part,
                        const float* __restrict__ w, const float* __restrict__ b,
                        short* __restrict__ hnp) {
    __shared__ __align__(16) float hs[DM];
    __shared__ float sm[8];
    int m = blockIdx.x, tid = threadIdx.x;
    float* row = res + (size_t)m * DM;
    float s = 0.f, ss = 0.f;
    for (int c = tid; c < DM; c += 256) {
        float v = row[c];
        if (ADD) {
            v += part[((size_t)0 * MROWS + m) * DM + c]
               + part[((size_t)1 * MROWS + m) * DM + c]
               + part[((size_t)2 * MROWS + m) * DM + c]
               + part[((size_t)3 * MROWS + m) * DM + c];
            row[c] = v;
        }
        hs[c] = v; s += v; ss += v * v;
    }
    #pragma unroll
    for (int o = 32; o; o >>= 1) { s += __shfl_xor(s, o); ss += __shfl_xor(ss, o); }
    int wid = tid >> 6;
    if ((tid & 63) == 0) { sm[wid] = s; sm[4 + wid] = ss; }
    __syncthreads();
    s = sm[0] + sm[1] + sm[2] + sm[3];
    ss = sm[4] + sm[5] + sm[6] + sm[7];
    float mu = s * (1.f / DM);
    float var = ss * (1.f / DM) - mu * mu;
    float rs = rsqrtf(var + 1e-5f);
    for (int G = tid; G < DM / 8; G += 256) {
        float4 f0 = *(const float4*)(hs + G * 8);
        float4 f1 = *(const float4*)(hs + G * 8 + 4);
        float4 w0 = *(const float4*)(w + G * 8);
        float4 w1 = *(const float4*)(w + G * 8 + 4);
        float4 b0 = *(const float4*)(b + G * 8);
        float4 b1 = *(const float4*)(b + G * 8 + 4);
        f0.x = (f0.x - mu) * rs * w0.x + b0.x; f0.y = (f0.y - mu) * rs * w0.y + b0.y;
        f0.z = (f0.z - mu) * rs * w0.z + b0.z; f0.w = (f0.w - mu) * rs * w0.w + b0.w;
        f1.x = (f1.x - mu) * rs * w1.x + b1.x; f1.y = (f1.y - mu) * rs * w1.y + b1.y;
        f1.z = (f1.z - mu) * rs * w1.z + b1.z; f1.w = (f1.w - mu) * rs * w1.w + b1.w;
        *(uint4*)&hnp[((size_t)G * 256 + m) * 8] = pack8(f0, f1);
    }
}

// ---------------------------------------------------------------------------
// MFMA GEMM, 3-stage pipeline with counted vmcnt (T3/T4-lite):
// C[256 x N] = A[256 x K] * W[N x K]^T   (EPI 0: store; 1: softplus(bias+acc))
// A pre-packed bf16 [G=k/8][m][8] staged via global_load_lds DMA, 2 steps ahead.
// W fp32 register-prefetched 2 steps ahead, packed to bf16 LDS 1 step ahead.
// Barriers are raw s_barrier preceded by asm "s_waitcnt vmcnt(5) lgkmcnt(0)"
// (the 5 = this step's 4 A-DMAs + 1 W-load stay IN FLIGHT across the barrier;
// everything older — i.e. next step's buffers — is guaranteed complete).
// Every barrier is immediately preceded by a memory-clobber asm => real fence.
// splitK writes partials at C + blockIdx.z*cStrideZ (no atomics).
template <int EPI, int NT>
__global__ __launch_bounds__(256)
void gemm_mfma(const short* __restrict__ Ap, const float* __restrict__ W, int ldw,
               float* __restrict__ C, int ldc, int kSteps, size_t cStrideZ,
               const float* __restrict__ bias) {
    constexpr int NC = NT / 16;                       // col fragments per wave
    __shared__ __align__(16) short a_sh[3][4][2056];  // [buf][kgroup][m*8]
    __shared__ __align__(16) short w_sh[3][4][NT * 8 + 8];
    const int tid = threadIdx.x;
    const int wz = tid >> 6, lane = tid & 63;
    const int g = lane >> 4, i16 = lane & 15;
    const int n0 = blockIdx.x * NT;
    const int sBeg = blockIdx.z * kSteps, sEnd = sBeg + kSteps;
    const int wr = tid >> 3;      // 0..31 (row within NT=32 tile)
    const int wq = tid & 7;       // quad-of-4-floats within 32-k
    C += (size_t)blockIdx.z * cStrideZ;

    f4_t acc[4][NC];
    #pragma unroll
    for (int r = 0; r < 4; ++r)
        #pragma unroll
        for (int c = 0; c < NC; ++c) acc[r][c] = (f4_t){0.f, 0.f, 0.f, 0.f};

    const short* arow = Ap + (size_t)tid * 8;
    const float* wbase = W + (size_t)(n0 + wr) * ldw + wq * 4;

    auto stageA = [&](int s, int buf) {
        #pragma unroll
        for (int it = 0; it < 4; ++it)
            __builtin_amdgcn_global_load_lds(
                (const __attribute__((address_space(1))) unsigned int*)(arow + (size_t)(s * 4 + it) * 2048),
                (__attribute__((address_space(3))) unsigned int*)&a_sh[buf][it][tid * 8], 16, 0, 0);
    };

    // ---- prologue: stage step sBeg (buf0) and sBeg+1 (buf1); kSteps >= 2 always
    stageA(sBeg, 0);                                         // 4 vm
    float4 wv0 = *(const float4*)(wbase + (size_t)sBeg * 32);       // 1 vm
    stageA(sBeg + 1, 1);                                     // 4 vm
    float4 wv1 = *(const float4*)(wbase + (size_t)(sBeg + 1) * 32); // 1 vm
    {
        uint2 p0 = {bfpair(wv0.x, wv0.y), bfpair(wv0.z, wv0.w)};   // compiler waits vmcnt(5) for wv0
        *(uint2*)&w_sh[0][wq >> 1][wr * 8 + (wq & 1) * 4] = p0;
    }
    asm volatile("s_waitcnt vmcnt(5) lgkmcnt(0)" ::: "memory");    // buf0 DMA done, w_sh[0] visible
    __builtin_amdgcn_s_barrier();

    float4 wv2;
    for (int t = sBeg; t < sEnd; ++t) {
        const int cur = (t - sBeg) % 3;
        const bool has2 = (t + 2 < sEnd);
        if (has2) {
            stageA(t + 2, (cur + 2) % 3);                           // 4 vm (into buffer of step t-1: readers done)
            wv2 = *(const float4*)(wbase + (size_t)(t + 2) * 32);   // 1 vm
        }
        bf8_t af[4], wf[NC];
        #pragma unroll
        for (int r = 0; r < 4; ++r)
            af[r] = *(const bf8_t*)&a_sh[cur][g][(wz * 64 + r * 16 + i16) * 8];
        #pragma unroll
        for (int c = 0; c < NC; ++c)
            wf[c] = *(const bf8_t*)&w_sh[cur][g][(c * 16 + i16) * 8];
        #pragma unroll
        for (int r = 0; r < 4; ++r)
            #pragma unroll
            for (int c = 0; c < NC; ++c)
                acc[r][c] = __builtin_amdgcn_mfma_f32_16x16x32_bf16(af[r], wf[c], acc[r][c], 0, 0, 0);
        if (t + 1 < sEnd) {
            // pack(wv1): compiler inserts vmcnt(5) (leaves step-t+2 ops in flight)
            uint2 p1 = {bfpair(wv1.x, wv1.y), bfpair(wv1.z, wv1.w)};
            *(uint2*)&w_sh[(cur + 1) % 3][wq >> 1][wr * 8 + (wq & 1) * 4] = p1;
            if (has2) {
                wv1 = wv2;
                asm volatile("s_waitcnt vmcnt(5) lgkmcnt(0)" ::: "memory");
            } else {
                asm volatile("s_waitcnt vmcnt(0) lgkmcnt(0)" ::: "memory");
            }
            __builtin_amdgcn_s_barrier();
        }
    }

    float bv[NC];
    if (EPI == 1) {
        #pragma unroll
        for (int c = 0; c < NC; ++c) bv[c] = bias[n0 + c * 16 + i16];
    }
    #pragma unroll
    for (int r = 0; r < 4; ++r) {
        #pragma unroll
        for (int c = 0; c < NC; ++c) {
            int n = n0 + c * 16 + i16;
            #pragma unroll
            for (int v = 0; v < 4; ++v) {
                int m = wz * 64 + r * 16 + g * 4 + v;
                float val = acc[r][c][v];
                if (EPI == 0) {
                    C[(size_t)m * ldc + n] = val;
                } else {
                    val += bv[c];
                    C[(size_t)m * ldc + n] = (val > 20.f) ? val : log1pf(expf(val));
                }
            }
        }
    }
}

// reduce 28 splitK partials of the B/C GEMM -> fp32 xdbl + packed bf16 xdblp[:224]
__global__ void reduce_pack_bc(const float* __restrict__ part, float* __restrict__ xdbl,
                               short* __restrict__ xdblp) {
    int m = blockIdx.x, tid = threadIdx.x;   // tid = col n
    float v = 0.f;
    #pragma unroll 4
    for (int z = 0; z < 28; ++z) v += part[((size_t)z * MROWS + m) * 256 + tid];
    xdbl[(size_t)m * 256 + tid] = v;
    __shared__ float buf[256];
    buf[tid] = v;
    __syncthreads();
    if (tid < DTR / 8) {
        float4 f0 = *(const float4*)&buf[tid * 8];
        float4 f1 = *(const float4*)&buf[tid * 8 + 4];
        *(uint4*)&xdblp[((size_t)tid * 256 + m) * 8] = pack8(f0, f1);
    }
}

// causal depthwise conv (DCONV=4) + silu; writes fp32 xq AND packed bf16 xqp
__global__ void conv_silu_pack(const float* __restrict__ xz, const float* __restrict__ cw,
                               const float* __restrict__ cb, float* __restrict__ xq,
                               short* __restrict__ xqp) {
    int bl = blockIdx.x;
    int b = bl / 125, l = bl % 125;
    size_t m = (size_t)b * LPAD + l;
    for (int c0 = threadIdx.x * 8; c0 < DI; c0 += 2048) {
        float v[8];
        float4 cb0 = *(const float4*)(cb + c0);
        float4 cb1 = *(const float4*)(cb + c0 + 4);
        v[0] = cb0.x; v[1] = cb0.y; v[2] = cb0.z; v[3] = cb0.w;
        v[4] = cb1.x; v[5] = cb1.y; v[6] = cb1.z; v[7] = cb1.w;
        #pragma unroll
        for (int j = 0; j < 4; ++j) {
            int lj = l - 3 + j;
            if (lj < 0) continue;
            const float* xr = xz + ((size_t)b * LPAD + lj) * (2 * DI) + c0;
            float4 x0 = *(const float4*)xr;
            float4 x1 = *(const float4*)(xr + 4);
            float xa[8] = {x0.x, x0.y, x0.z, x0.w, x1.x, x1.y, x1.z, x1.w};
            #pragma unroll
            for (int k = 0; k < 8; ++k)
                v[k] = fmaf(xa[k], cw[(c0 + k) * 4 + j], v[k]);
        }
        float4 o0, o1;
        #pragma unroll
        for (int k = 0; k < 8; ++k) {
            float sv = v[k] / (1.f + expf(-v[k]));
            if (k < 4) (&o0.x)[k] = sv; else (&o1.x)[k - 4] = sv;
        }
        *(float4*)(xq + m * DI + c0) = o0;
        *(float4*)(xq + m * DI + c0 + 4) = o1;
        *(uint4*)&xqp[(((size_t)c0 / 8) * 256 + m) * 8] = pack8(o0, o1);
    }
}

// selective scan: 4 threads per channel (4 states each), software-pipelined.
// Also writes packed bf16 ybp directly (fuses the former pack_rows(yb) kernel).
__global__ void scan_kernel(const float* __restrict__ delta, const float* __restrict__ xq,
                            const float* __restrict__ xdbl, const float* __restrict__ xz,
                            const float* __restrict__ Alog, const float* __restrict__ Dp,
                            float* __restrict__ y, short* __restrict__ ybp) {
    int tid = threadIdx.x;
    int sg = tid & 3;                          // state group: states sg*4..sg*4+3
    int c = blockIdx.x * 64 + (tid >> 2);      // channel 0..7167
    int b = blockIdx.y;
    float As[4], st[4];
    #pragma unroll
    for (int k = 0; k < 4; ++k) {
        As[k] = -expf(Alog[(size_t)c * DSTATE + sg * 4 + k]);
        st[k] = 0.f;
    }
    float dp = Dp[c];
    size_t mb = (size_t)b * LPAD;
    float d_c = delta[mb * DI + c];
    float x_c = xq[mb * DI + c];
    float z_c = xz[mb * (2 * DI) + DI + c];
    float4 B_c = *(const float4*)(xdbl + mb * 256 + DTR + sg * 4);
    float4 C_c = *(const float4*)(xdbl + mb * 256 + DTR + DSTATE + sg * 4);
    for (int l = 0; l < LOUT; ++l) {
        float d_n = d_c, x_n = x_c, z_n = z_c;
        float4 B_n = B_c, C_n = C_c;
        if (l + 1 < LOUT) {
            size_t m = mb + l + 1;
            d_n = delta[m * DI + c];
            x_n = xq[m * DI + c];
            z_n = xz[m * (2 * DI) + DI + c];
            B_n = *(const float4*)(xdbl + m * 256 + DTR + sg * 4);
            C_n = *(const float4*)(xdbl + m * 256 + DTR + DSTATE + sg * 4);
        }
        float du = d_c * x_c;
        float yv = 0.f;
        #pragma unroll
        for (int k = 0; k < 4; ++k) {
            st[k] = fmaf(expf(d_c * As[k]), st[k], du * (&B_c.x)[k]);
            yv = fmaf(st[k], (&C_c.x)[k], yv);
        }
        yv += __shfl_xor(yv, 1);
        yv += __shfl_xor(yv, 2);
        if (sg == 0) {
            float yout = (yv + x_c * dp) * (z_c / (1.f + expf(-z_c)));
            size_t m = mb + l;
            y[m * DI + c] = yout;
            ybp[((size_t)(c >> 3) * 256 + m) * 8 + (c & 7)] =
                (short)(bfpair(yout, 0.f) & 0xffffu);
        }
        d_c = d_n; x_c = x_n; z_c = z_n; B_c = B_n; C_c = C_n;
    }
}

// final: res + sum of 4 out_proj partials -> layernorm -> fc head
__global__ void ln_fc(const float* __restrict__ res, const float* __restrict__ part,
                      const float* __restrict__ wf, const float* __restrict__ bf,
                      const float* __restrict__ fcw, const float* __restrict__ fcb,
                      float* __restrict__ out) {
    __shared__ __align__(16) float hs[DM];
    __shared__ float sm[8];
    int bl = blockIdx.x;
    int b = bl / 125, l = bl % 125;
    size_t m = (size_t)b * LPAD + l;
    int tid = threadIdx.x;
    const float* row = res + m * DM;
    float s = 0.f, ss = 0.f;
    for (int c = tid; c < DM; c += 256) {
        float v = row[c]
                + part[((size_t)0 * MROWS + m) * DM + c]
                + part[((size_t)1 * MROWS + m) * DM + c]
                + part[((size_t)2 * MROWS + m) * DM + c]
                + part[((size_t)3 * MROWS + m) * DM + c];
        hs[c] = v; s += v; ss += v * v;
    }
    #pragma unroll
    for (int o = 32; o; o >>= 1) { s += __shfl_xor(s, o); ss += __shfl_xor(ss, o); }
    int wid = tid >> 6;
    if ((tid & 63) == 0) { sm[wid] = s; sm[4 + wid] = ss; }
    __syncthreads();
    s = sm[0] + sm[1] + sm[2] + sm[3];
    ss = sm[4] + sm[5] + sm[6] + sm[7];
    float mu = s * (1.f / DM);
    float var = ss * (1.f / DM) - mu * mu;
    float rs = rsqrtf(var + 1e-5f);
    for (int c = tid; c < DM; c += 256) hs[c] = (hs[c] - mu) * rs * wf[c] + bf[c];
    __syncthreads();
    int lane = tid & 63;
    for (int n = wid; n < NCLS; n += 4) {
        const float* wrow = fcw + (size_t)n * DM;
        float a0 = 0.f, a1 = 0.f, a2 = 0.f, a3 = 0.f;
        for (int k = lane; k < DM; k += 256) {
            a0 = fmaf(hs[k],       wrow[k],       a0);
            a1 = fmaf(hs[k + 64],  wrow[k + 64],  a1);
            a2 = fmaf(hs[k + 128], wrow[k + 128], a2);
            a3 = fmaf(hs[k + 192], wrow[k + 192], a3);
        }
        float acc = (a0 + a1) + (a2 + a3);
        #pragma unroll
        for (int o = 32; o; o >>= 1) acc += __shfl_xor(acc, o);
        if (lane == 0) out[((size_t)b * LOUT + l) * NCLS + n] = acc + fcb[n];
    }
}

// ---------------------------------------------------------------------------
extern "C" void kernel_launch(void* const* d_in, const int* in_sizes, int n_in,
                              void* d_out, int out_size, void* d_ws, size_t ws_size,
                              hipStream_t stream) {
    (void)in_sizes; (void)n_in; (void)out_size; (void)ws_size;
    const float* nI   = (const float*)d_in[0];
    const float* dw   = (const float*)d_in[1];
    const float* db   = (const float*)d_in[2];
    const float* nw   = (const float*)d_in[3];
    const float* nb   = (const float*)d_in[4];
    const float* ipw  = (const float*)d_in[5];
    const float* cw   = (const float*)d_in[6];
    const float* cb   = (const float*)d_in[7];
    const float* xpw  = (const float*)d_in[8];
    const float* dtw  = (const float*)d_in[9];
    const float* dtb  = (const float*)d_in[10];
    const float* Alog = (const float*)d_in[11];
    const float* Dp   = (const float*)d_in[12];
    const float* opw  = (const float*)d_in[13];
    const float* nfw  = (const float*)d_in[14];
    const float* nfb  = (const float*)d_in[15];
    const float* fcw  = (const float*)d_in[16];
    const float* fcb  = (const float*)d_in[17];
    const int*   dayI = (const int*)d_in[18];
    float* out = (float*)d_out;

    float* wsf = (float*)d_ws;
    float* t_full   = wsf; wsf += 262144;                    // B*T*ND
    float* res      = wsf; wsf += (size_t)MROWS * DM;
    float* xz       = wsf; wsf += (size_t)MROWS * 2 * DI;
    float* xq       = wsf; wsf += (size_t)MROWS * DI;
    float* xdbl     = wsf; wsf += (size_t)MROWS * 256;
    float* delta    = wsf; wsf += (size_t)MROWS * DI;
    float* yb       = wsf; wsf += (size_t)MROWS * DI;
    float* xdbl_prt = wsf; wsf += (size_t)28 * MROWS * 256;  // B/C splitK partials
    float* res_prt  = wsf; wsf += (size_t)4 * MROWS * DM;    // out_proj splitK partials
    short* wss = (short*)wsf;
    short* hnp   = wss; wss += (size_t)MROWS * DM;           // packed bf16
    short* xqp   = wss; wss += (size_t)MROWS * DI;
    short* xdblp = wss; wss += (size_t)MROWS * DTR;
    short* ybp   = wss; wss += (size_t)MROWS * DI;

    day_proj<<<dim3(BATCH * TSEQ), 256, 0, stream>>>(nI, dw, db, dayI, t_full);
    window_k<<<dim3(MROWS), 256, 0, stream>>>(t_full, res);

    for (int i = 0; i < 2; ++i) {
        if (i == 0)
            ln_pack<false><<<dim3(MROWS), 256, 0, stream>>>(
                res, nullptr, nw, nb, hnp);
        else
            ln_pack<true><<<dim3(MROWS), 256, 0, stream>>>(
                res, res_prt, nw + (size_t)DM, nb + (size_t)DM, hnp);
        // xz = hn @ ipw^T   (N=14336, K=3584): 448 blocks, 112 k-steps
        gemm_mfma<0, 32><<<dim3(448, 1, 1), 256, 0, stream>>>(
            hnp, ipw + (size_t)i * 2 * DI * DM, DM, xz, 2 * DI, 112, 0, nullptr);
        conv_silu_pack<<<dim3(BATCH * LOUT), 256, 0, stream>>>(
            xz, cw + (size_t)i * DI * 4, cb + (size_t)i * DI, xq, xqp);
        // xdbl partials = xq @ xpw^T (N=256, K=7168): splitK=28 -> 224 blocks, no atomics
        gemm_mfma<0, 32><<<dim3(8, 1, 28), 256, 0, stream>>>(
            xqp, xpw + (size_t)i * 256 * DI, DI, xdbl_prt, 256, 8,
            (size_t)MROWS * 256, nullptr);
        reduce_pack_bc<<<dim3(MROWS), 256, 0, stream>>>(xdbl_prt, xdbl, xdblp);
        // delta = softplus(xdbl[:, :224] @ dtw^T + dtb)  (N=7168, K=224): 224 blocks
        gemm_mfma<1, 32><<<dim3(224, 1, 1), 256, 0, stream>>>(
            xdblp, dtw + (size_t)i * DI * DTR, DTR, delta, DI, 7, 0, dtb + (size_t)i * DI);
        scan_kernel<<<dim3(DI / 64, BATCH), 256, 0, stream>>>(
            delta, xq, xdbl, xz, Alog + (size_t)i * DI * DSTATE, Dp + (size_t)i * DI, yb, ybp);
        // res_prt = yb @ opw^T  (N=3584, K=7168): splitK=4 -> 448 blocks, no atomics
        gemm_mfma<0, 32><<<dim3(112, 1, 4), 256, 0, stream>>>(
            ybp, opw + (size_t)i * DM * DI, DI, res_prt, DM, 56,
            (size_t)MROWS * DM, nullptr);
    }

    ln_fc<<<dim3(BATCH * LOUT), 256, 0, stream>>>(res, res_prt, nfw, nfb, fcw, fcb, out);
}

// Round 4
// 1273.443 us; speedup vs baseline: 1.0841x; 1.0109x over previous
//
#include <hip/hip_runtime.h>
#include <hip/hip_bf16.h>
#include <math.h>

// ---- problem constants ----
#define BATCH   2
#define TSEQ    512
#define NDIM    256
#define STRIDE_ 4
#define KLEN    14
#define DM      3584        // NDIM*KLEN
#define DI      7168        // 2*DM
#define DTR     224
#define DSTATE  16
#define NCLS    41
#define LOUT    125
#define LPAD    128         // padded rows per batch
#define MROWS   256         // BATCH*LPAD

typedef __attribute__((ext_vector_type(8))) short bf8_t;   // 8 bf16
typedef __attribute__((ext_vector_type(4))) float f4_t;    // 4 fp32 acc

// fp32 -> bf16 RNE, two at a time
__device__ inline unsigned bfpair(float a, float b) {
    unsigned ua = __builtin_bit_cast(unsigned, a);
    unsigned ub = __builtin_bit_cast(unsigned, b);
    ua = (ua + 0x7fffu + ((ua >> 16) & 1u)) >> 16;
    ub = (ub + 0x7fffu + ((ub >> 16) & 1u)) >> 16;
    return ua | (ub << 16);
}
__device__ inline uint4 pack8(float4 a, float4 b) {
    return make_uint4(bfpair(a.x, a.y), bfpair(a.z, a.w),
                      bfpair(b.x, b.y), bfpair(b.z, b.w));
}

// ---------------------------------------------------------------------------
// day projection + softsign
__global__ void day_proj(const float* __restrict__ nI, const float* __restrict__ dw,
                         const float* __restrict__ db, const int* __restrict__ dayIdx,
                         float* __restrict__ t_full) {
    int bi = blockIdx.x;               // b*512 + i
    int b = bi >> 9;
    int di = dayIdx[b];
    int tid = threadIdx.x;             // k
    __shared__ float a_sh[256];
    a_sh[tid] = nI[(size_t)bi * 256 + tid];
    __syncthreads();
    const float* w = dw + (size_t)di * 65536;
    float acc = db[(size_t)di * 256 + tid];
    #pragma unroll 8
    for (int d = 0; d < 256; ++d) acc = fmaf(a_sh[d], w[d * 256 + tid], acc);
    t_full[(size_t)bi * 256 + tid] = acc / (1.f + fabsf(acc));
}

// window gather + zero the pad rows (l >= 125)
__global__ void window_k(const float* __restrict__ t_full, float* __restrict__ res) {
    int bl = blockIdx.x;               // 0..255
    int b = bl >> 7, l = bl & 127;
    size_t m = (size_t)b * LPAD + l;
    if (l >= LOUT) {
        for (int c = threadIdx.x; c < DM; c += 256) res[m * DM + c] = 0.f;
        return;
    }
    for (int c = threadIdx.x; c < DM; c += 256) {
        int d = c / KLEN, j = c - d * KLEN;
        res[m * DM + c] = t_full[((size_t)b * TSEQ + l * STRIDE_ + j) * 256 + d];
    }
}

// layernorm over DM -> packed bf16 A in fragment-major [G=k/8][m][8].
// ADD variant fuses: res += sum of 4 out_proj splitK partials (residual add),
// writes res back, LNs the updated row. Row staged in LDS to avoid re-read.
template <bool ADD>
__global__ void ln_pack(float* __restrict__ res, const float* __restrict__ part,
                        const float* __restrict__ w, const float* __restrict__ b,
                        short* __restrict__ hnp) {
    __shared__ __align__(16) float hs[DM];
    __shared__ float sm[8];
    int m = blockIdx.x, tid = threadIdx.x;
    float* row = res + (size_t)m * DM;
    float s = 0.f, ss = 0.f;
    for (int c = tid; c < DM; c += 256) {
        float v = row[c];
        if (ADD) {
            v += part[((size_t)0 * MROWS + m) * DM + c]
               + part[((size_t)1 * MROWS + m) * DM + c]
               + part[((size_t)2 * MROWS + m) * DM + c]
               + part[((size_t)3 * MROWS + m) * DM + c];
            row[c] = v;
        }
        hs[c] = v; s += v; ss += v * v;
    }
    #pragma unroll
    for (int o = 32; o; o >>= 1) { s += __shfl_xor(s, o); ss += __shfl_xor(ss, o); }
    int wid = tid >> 6;
    if ((tid & 63) == 0) { sm[wid] = s; sm[4 + wid] = ss; }
    __syncthreads();
    s = sm[0] + sm[1] + sm[2] + sm[3];
    ss = sm[4] + sm[5] + sm[6] + sm[7];
    float mu = s * (1.f / DM);
    float var = ss * (1.f / DM) - mu * mu;
    float rs = rsqrtf(var + 1e-5f);
    for (int G = tid; G < DM / 8; G += 256) {
        float4 f0 = *(const float4*)(hs + G * 8);
        float4 f1 = *(const float4*)(hs + G * 8 + 4);
        float4 w0 = *(const float4*)(w + G * 8);
        float4 w1 = *(const float4*)(w + G * 8 + 4);
        float4 b0 = *(const float4*)(b + G * 8);
        float4 b1 = *(const float4*)(b + G * 8 + 4);
        f0.x = (f0.x - mu) * rs * w0.x + b0.x; f0.y = (f0.y - mu) * rs * w0.y + b0.y;
        f0.z = (f0.z - mu) * rs * w0.z + b0.z; f0.w = (f0.w - mu) * rs * w0.w + b0.w;
        f1.x = (f1.x - mu) * rs * w1.x + b1.x; f1.y = (f1.y - mu) * rs * w1.y + b1.y;
        f1.z = (f1.z - mu) * rs * w1.z + b1.z; f1.w = (f1.w - mu) * rs * w1.w + b1.w;
        *(uint4*)&hnp[((size_t)G * 256 + m) * 8] = pack8(f0, f1);
    }
}

// ---------------------------------------------------------------------------
// MFMA GEMM, 4-stage pipeline (prefetch 3 k-steps ahead), counted vmcnt:
// C[256 x N] = A[256 x K] * W[N x K]^T   (EPI 0: store; 1: softplus(bias+acc))
// A pre-packed bf16 [G=k/8][m][8] staged via global_load_lds DMA, 3 steps ahead.
// W fp32 register-prefetched 3 steps ahead (wv1/wv2/wv3 rotate), packed 1 ahead.
// Steady-state barrier wait: s_waitcnt vmcnt(10) — leaves the 10 loads of steps
// t+2 and t+3 in flight; drains step t+1's (issued ~2.2 iterations earlier).
// splitK writes partials at C + blockIdx.z*cStrideZ (no atomics). kSteps >= 3.
template <int EPI, int NT>
__global__ __launch_bounds__(256)
void gemm_mfma(const short* __restrict__ Ap, const float* __restrict__ W, int ldw,
               float* __restrict__ C, int ldc, int kSteps, size_t cStrideZ,
               const float* __restrict__ bias) {
    constexpr int NC = NT / 16;                       // col fragments per wave
    __shared__ __align__(16) short a_sh[4][4][2056];  // [buf][kgroup][m*8]  65.8 KB
    __shared__ __align__(16) short w_sh[4][4][NT * 8 + 8];
    const int tid = threadIdx.x;
    const int wz = tid >> 6, lane = tid & 63;
    const int g = lane >> 4, i16 = lane & 15;
    const int n0 = blockIdx.x * NT;
    const int sBeg = blockIdx.z * kSteps, sEnd = sBeg + kSteps;
    const int wr = tid >> 3;      // 0..31 (row within NT=32 tile)
    const int wq = tid & 7;       // quad-of-4-floats within 32-k
    C += (size_t)blockIdx.z * cStrideZ;

    f4_t acc[4][NC];
    #pragma unroll
    for (int r = 0; r < 4; ++r)
        #pragma unroll
        for (int c = 0; c < NC; ++c) acc[r][c] = (f4_t){0.f, 0.f, 0.f, 0.f};

    const short* arow = Ap + (size_t)tid * 8;
    const float* wbase = W + (size_t)(n0 + wr) * ldw + wq * 4;

    auto stageA = [&](int s, int buf) {
        #pragma unroll
        for (int it = 0; it < 4; ++it)
            __builtin_amdgcn_global_load_lds(
                (const __attribute__((address_space(1))) unsigned int*)(arow + (size_t)(s * 4 + it) * 2048),
                (__attribute__((address_space(3))) unsigned int*)&a_sh[buf][it][tid * 8], 16, 0, 0);
    };

    // ---- prologue: stage steps s0..s0+2 into buf0..2 (kSteps >= 3 always)
    stageA(sBeg, 0);                                                 // 4 vm
    float4 wv0 = *(const float4*)(wbase + (size_t)sBeg * 32);        // 1 vm
    stageA(sBeg + 1, 1);                                             // 4 vm
    float4 wv1 = *(const float4*)(wbase + (size_t)(sBeg + 1) * 32);  // 1 vm
    stageA(sBeg + 2, 2);                                             // 4 vm
    float4 wv2 = *(const float4*)(wbase + (size_t)(sBeg + 2) * 32);  // 1 vm
    {
        uint2 p0 = {bfpair(wv0.x, wv0.y), bfpair(wv0.z, wv0.w)};     // compiler: vmcnt(10) for wv0
        *(uint2*)&w_sh[0][wq >> 1][wr * 8 + (wq & 1) * 4] = p0;
    }
    asm volatile("s_waitcnt vmcnt(10) lgkmcnt(0)" ::: "memory");     // buf0 DMA done, w_sh[0] visible
    __builtin_amdgcn_s_barrier();

    float4 wv3;
    for (int t = sBeg; t < sEnd; ++t) {
        const int cur = (t - sBeg) & 3;
        const bool has3 = (t + 3 < sEnd);
        if (has3) {
            stageA(t + 3, (cur + 3) & 3);                            // into buffer of step t-1 (readers done)
            wv3 = *(const float4*)(wbase + (size_t)(t + 3) * 32);
        }
        bf8_t af[4], wf[NC];
        #pragma unroll
        for (int r = 0; r < 4; ++r)
            af[r] = *(const bf8_t*)&a_sh[cur][g][(wz * 64 + r * 16 + i16) * 8];
        #pragma unroll
        for (int c = 0; c < NC; ++c)
            wf[c] = *(const bf8_t*)&w_sh[cur][g][(c * 16 + i16) * 8];
        #pragma unroll
        for (int r = 0; r < 4; ++r)
            #pragma unroll
            for (int c = 0; c < NC; ++c)
                acc[r][c] = __builtin_amdgcn_mfma_f32_16x16x32_bf16(af[r], wf[c], acc[r][c], 0, 0, 0);
        if (t + 1 < sEnd) {
            // pack W for step t+1 (wv1 loaded 3 iterations back; compiler-counted wait)
            uint2 p1 = {bfpair(wv1.x, wv1.y), bfpair(wv1.z, wv1.w)};
            *(uint2*)&w_sh[(cur + 1) & 3][wq >> 1][wr * 8 + (wq & 1) * 4] = p1;
            wv1 = wv2; wv2 = wv3;
            if (has3) {
                asm volatile("s_waitcnt vmcnt(10) lgkmcnt(0)" ::: "memory"); // t+1 ready; t+2,t+3 in flight
            } else if (t + 2 < sEnd) {
                asm volatile("s_waitcnt vmcnt(5) lgkmcnt(0)" ::: "memory");  // t+1 ready; t+2 in flight
            } else {
                asm volatile("s_waitcnt vmcnt(0) lgkmcnt(0)" ::: "memory");  // final drain
            }
            __builtin_amdgcn_s_barrier();
        }
    }

    float bv[NC];
    if (EPI == 1) {
        #pragma unroll
        for (int c = 0; c < NC; ++c) bv[c] = bias[n0 + c * 16 + i16];
    }
    #pragma unroll
    for (int r = 0; r < 4; ++r) {
        #pragma unroll
        for (int c = 0; c < NC; ++c) {
            int n = n0 + c * 16 + i16;
            #pragma unroll
            for (int v = 0; v < 4; ++v) {
                int m = wz * 64 + r * 16 + g * 4 + v;
                float val = acc[r][c][v];
                if (EPI == 0) {
                    C[(size_t)m * ldc + n] = val;
                } else {
                    val += bv[c];
                    C[(size_t)m * ldc + n] = (val > 20.f) ? val : log1pf(expf(val));
                }
            }
        }
    }
}

// reduce 28 splitK partials of the B/C GEMM -> fp32 xdbl + packed bf16 xdblp[:224]
__global__ void reduce_pack_bc(const float* __restrict__ part, float* __restrict__ xdbl,
                               short* __restrict__ xdblp) {
    int m = blockIdx.x, tid = threadIdx.x;   // tid = col n
    float v = 0.f;
    #pragma unroll 4
    for (int z = 0; z < 28; ++z) v += part[((size_t)z * MROWS + m) * 256 + tid];
    xdbl[(size_t)m * 256 + tid] = v;
    __shared__ float buf[256];
    buf[tid] = v;
    __syncthreads();
    if (tid < DTR / 8) {
        float4 f0 = *(const float4*)&buf[tid * 8];
        float4 f1 = *(const float4*)&buf[tid * 8 + 4];
        *(uint4*)&xdblp[((size_t)tid * 256 + m) * 8] = pack8(f0, f1);
    }
}

// causal depthwise conv (DCONV=4) + silu; writes fp32 xq AND packed bf16 xqp
__global__ void conv_silu_pack(const float* __restrict__ xz, const float* __restrict__ cw,
                               const float* __restrict__ cb, float* __restrict__ xq,
                               short* __restrict__ xqp) {
    int bl = blockIdx.x;
    int b = bl / 125, l = bl % 125;
    size_t m = (size_t)b * LPAD + l;
    for (int c0 = threadIdx.x * 8; c0 < DI; c0 += 2048) {
        float v[8];
        float4 cb0 = *(const float4*)(cb + c0);
        float4 cb1 = *(const float4*)(cb + c0 + 4);
        v[0] = cb0.x; v[1] = cb0.y; v[2] = cb0.z; v[3] = cb0.w;
        v[4] = cb1.x; v[5] = cb1.y; v[6] = cb1.z; v[7] = cb1.w;
        #pragma unroll
        for (int j = 0; j < 4; ++j) {
            int lj = l - 3 + j;
            if (lj < 0) continue;
            const float* xr = xz + ((size_t)b * LPAD + lj) * (2 * DI) + c0;
            float4 x0 = *(const float4*)xr;
            float4 x1 = *(const float4*)(xr + 4);
            float xa[8] = {x0.x, x0.y, x0.z, x0.w, x1.x, x1.y, x1.z, x1.w};
            #pragma unroll
            for (int k = 0; k < 8; ++k)
                v[k] = fmaf(xa[k], cw[(c0 + k) * 4 + j], v[k]);
        }
        float4 o0, o1;
        #pragma unroll
        for (int k = 0; k < 8; ++k) {
            float sv = v[k] / (1.f + expf(-v[k]));
            if (k < 4) (&o0.x)[k] = sv; else (&o1.x)[k - 4] = sv;
        }
        *(float4*)(xq + m * DI + c0) = o0;
        *(float4*)(xq + m * DI + c0 + 4) = o1;
        *(uint4*)&xqp[(((size_t)c0 / 8) * 256 + m) * 8] = pack8(o0, o1);
    }
}

// selective scan: 4 threads per channel (4 states each), software-pipelined.
// Also writes packed bf16 ybp directly (fuses the former pack_rows(yb) kernel).
__global__ void scan_kernel(const float* __restrict__ delta, const float* __restrict__ xq,
                            const float* __restrict__ xdbl, const float* __restrict__ xz,
                            const float* __restrict__ Alog, const float* __restrict__ Dp,
                            float* __restrict__ y, short* __restrict__ ybp) {
    int tid = threadIdx.x;
    int sg = tid & 3;                          // state group: states sg*4..sg*4+3
    int c = blockIdx.x * 64 + (tid >> 2);      // channel 0..7167
    int b = blockIdx.y;
    float As[4], st[4];
    #pragma unroll
    for (int k = 0; k < 4; ++k) {
        As[k] = -expf(Alog[(size_t)c * DSTATE + sg * 4 + k]);
        st[k] = 0.f;
    }
    float dp = Dp[c];
    size_t mb = (size_t)b * LPAD;
    float d_c = delta[mb * DI + c];
    float x_c = xq[mb * DI + c];
    float z_c = xz[mb * (2 * DI) + DI + c];
    float4 B_c = *(const float4*)(xdbl + mb * 256 + DTR + sg * 4);
    float4 C_c = *(const float4*)(xdbl + mb * 256 + DTR + DSTATE + sg * 4);
    for (int l = 0; l < LOUT; ++l) {
        float d_n = d_c, x_n = x_c, z_n = z_c;
        float4 B_n = B_c, C_n = C_c;
        if (l + 1 < LOUT) {
            size_t m = mb + l + 1;
            d_n = delta[m * DI + c];
            x_n = xq[m * DI + c];
            z_n = xz[m * (2 * DI) + DI + c];
            B_n = *(const float4*)(xdbl + m * 256 + DTR + sg * 4);
            C_n = *(const float4*)(xdbl + m * 256 + DTR + DSTATE + sg * 4);
        }
        float du = d_c * x_c;
        float yv = 0.f;
        #pragma unroll
        for (int k = 0; k < 4; ++k) {
            st[k] = fmaf(expf(d_c * As[k]), st[k], du * (&B_c.x)[k]);
            yv = fmaf(st[k], (&C_c.x)[k], yv);
        }
        yv += __shfl_xor(yv, 1);
        yv += __shfl_xor(yv, 2);
        if (sg == 0) {
            float yout = (yv + x_c * dp) * (z_c / (1.f + expf(-z_c)));
            size_t m = mb + l;
            y[m * DI + c] = yout;
            ybp[((size_t)(c >> 3) * 256 + m) * 8 + (c & 7)] =
                (short)(bfpair(yout, 0.f) & 0xffffu);
        }
        d_c = d_n; x_c = x_n; z_c = z_n; B_c = B_n; C_c = C_n;
    }
}

// final: res + sum of 4 out_proj partials -> layernorm -> fc head
__global__ void ln_fc(const float* __restrict__ res, const float* __restrict__ part,
                      const float* __restrict__ wf, const float* __restrict__ bf,
                      const float* __restrict__ fcw, const float* __restrict__ fcb,
                      float* __restrict__ out) {
    __shared__ __align__(16) float hs[DM];
    __shared__ float sm[8];
    int bl = blockIdx.x;
    int b = bl / 125, l = bl % 125;
    size_t m = (size_t)b * LPAD + l;
    int tid = threadIdx.x;
    const float* row = res + m * DM;
    float s = 0.f, ss = 0.f;
    for (int c = tid; c < DM; c += 256) {
        float v = row[c]
                + part[((size_t)0 * MROWS + m) * DM + c]
                + part[((size_t)1 * MROWS + m) * DM + c]
                + part[((size_t)2 * MROWS + m) * DM + c]
                + part[((size_t)3 * MROWS + m) * DM + c];
        hs[c] = v; s += v; ss += v * v;
    }
    #pragma unroll
    for (int o = 32; o; o >>= 1) { s += __shfl_xor(s, o); ss += __shfl_xor(ss, o); }
    int wid = tid >> 6;
    if ((tid & 63) == 0) { sm[wid] = s; sm[4 + wid] = ss; }
    __syncthreads();
    s = sm[0] + sm[1] + sm[2] + sm[3];
    ss = sm[4] + sm[5] + sm[6] + sm[7];
    float mu = s * (1.f / DM);
    float var = ss * (1.f / DM) - mu * mu;
    float rs = rsqrtf(var + 1e-5f);
    for (int c = tid; c < DM; c += 256) hs[c] = (hs[c] - mu) * rs * wf[c] + bf[c];
    __syncthreads();
    int lane = tid & 63;
    for (int n = wid; n < NCLS; n += 4) {
        const float* wrow = fcw + (size_t)n * DM;
        float a0 = 0.f, a1 = 0.f, a2 = 0.f, a3 = 0.f;
        for (int k = lane; k < DM; k += 256) {
            a0 = fmaf(hs[k],       wrow[k],       a0);
            a1 = fmaf(hs[k + 64],  wrow[k + 64],  a1);
            a2 = fmaf(hs[k + 128], wrow[k + 128], a2);
            a3 = fmaf(hs[k + 192], wrow[k + 192], a3);
        }
        float acc = (a0 + a1) + (a2 + a3);
        #pragma unroll
        for (int o = 32; o; o >>= 1) acc += __shfl_xor(acc, o);
        if (lane == 0) out[((size_t)b * LOUT + l) * NCLS + n] = acc + fcb[n];
    }
}

// ---------------------------------------------------------------------------
extern "C" void kernel_launch(void* const* d_in, const int* in_sizes, int n_in,
                              void* d_out, int out_size, void* d_ws, size_t ws_size,
                              hipStream_t stream) {
    (void)in_sizes; (void)n_in; (void)out_size; (void)ws_size;
    const float* nI   = (const float*)d_in[0];
    const float* dw   = (const float*)d_in[1];
    const float* db   = (const float*)d_in[2];
    const float* nw   = (const float*)d_in[3];
    const float* nb   = (const float*)d_in[4];
    const float* ipw  = (const float*)d_in[5];
    const float* cw   = (const float*)d_in[6];
    const float* cb   = (const float*)d_in[7];
    const float* xpw  = (const float*)d_in[8];
    const float* dtw  = (const float*)d_in[9];
    const float* dtb  = (const float*)d_in[10];
    const float* Alog = (const float*)d_in[11];
    const float* Dp   = (const float*)d_in[12];
    const float* opw  = (const float*)d_in[13];
    const float* nfw  = (const float*)d_in[14];
    const float* nfb  = (const float*)d_in[15];
    const float* fcw  = (const float*)d_in[16];
    const float* fcb  = (const float*)d_in[17];
    const int*   dayI = (const int*)d_in[18];
    float* out = (float*)d_out;

    float* wsf = (float*)d_ws;
    float* t_full   = wsf; wsf += 262144;                    // B*T*ND
    float* res      = wsf; wsf += (size_t)MROWS * DM;
    float* xz       = wsf; wsf += (size_t)MROWS * 2 * DI;
    float* xq       = wsf; wsf += (size_t)MROWS * DI;
    float* xdbl     = wsf; wsf += (size_t)MROWS * 256;
    float* delta    = wsf; wsf += (size_t)MROWS * DI;
    float* yb       = wsf; wsf += (size_t)MROWS * DI;
    float* xdbl_prt = wsf; wsf += (size_t)28 * MROWS * 256;  // B/C splitK partials
    float* res_prt  = wsf; wsf += (size_t)4 * MROWS * DM;    // out_proj splitK partials
    short* wss = (short*)wsf;
    short* hnp   = wss; wss += (size_t)MROWS * DM;           // packed bf16
    short* xqp   = wss; wss += (size_t)MROWS * DI;
    short* xdblp = wss; wss += (size_t)MROWS * DTR;
    short* ybp   = wss; wss += (size_t)MROWS * DI;

    day_proj<<<dim3(BATCH * TSEQ), 256, 0, stream>>>(nI, dw, db, dayI, t_full);
    window_k<<<dim3(MROWS), 256, 0, stream>>>(t_full, res);

    for (int i = 0; i < 2; ++i) {
        if (i == 0)
            ln_pack<false><<<dim3(MROWS), 256, 0, stream>>>(
                res, nullptr, nw, nb, hnp);
        else
            ln_pack<true><<<dim3(MROWS), 256, 0, stream>>>(
                res, res_prt, nw + (size_t)DM, nb + (size_t)DM, hnp);
        // xz = hn @ ipw^T   (N=14336, K=3584): 448 blocks, 112 k-steps
        gemm_mfma<0, 32><<<dim3(448, 1, 1), 256, 0, stream>>>(
            hnp, ipw + (size_t)i * 2 * DI * DM, DM, xz, 2 * DI, 112, 0, nullptr);
        conv_silu_pack<<<dim3(BATCH * LOUT), 256, 0, stream>>>(
            xz, cw + (size_t)i * DI * 4, cb + (size_t)i * DI, xq, xqp);
        // xdbl partials = xq @ xpw^T (N=256, K=7168): splitK=28 -> 224 blocks, no atomics
        gemm_mfma<0, 32><<<dim3(8, 1, 28), 256, 0, stream>>>(
            xqp, xpw + (size_t)i * 256 * DI, DI, xdbl_prt, 256, 8,
            (size_t)MROWS * 256, nullptr);
        reduce_pack_bc<<<dim3(MROWS), 256, 0, stream>>>(xdbl_prt, xdbl, xdblp);
        // delta = softplus(xdbl[:, :224] @ dtw^T + dtb)  (N=7168, K=224): 224 blocks
        gemm_mfma<1, 32><<<dim3(224, 1, 1), 256, 0, stream>>>(
            xdblp, dtw + (size_t)i * DI * DTR, DTR, delta, DI, 7, 0, dtb + (size_t)i * DI);
        scan_kernel<<<dim3(DI / 64, BATCH), 256, 0, stream>>>(
            delta, xq, xdbl, xz, Alog + (size_t)i * DI * DSTATE, Dp + (size_t)i * DI, yb, ybp);
        // res_prt = yb @ opw^T  (N=3584, K=7168): splitK=4 -> 448 blocks, no atomics
        gemm_mfma<0, 32><<<dim3(112, 1, 4), 256, 0, stream>>>(
            ybp, opw + (size_t)i * DM * DI, DI, res_prt, DM, 56,
            (size_t)MROWS * DM, nullptr);
    }

    ln_fc<<<dim3(BATCH * LOUT), 256, 0, stream>>>(res, res_prt, nfw, nfb, fcw, fcb, out);
}